// Round 1
// baseline (3202.826 us; speedup 1.0000x reference)
//
#include <hip/hip_runtime.h>
#include <hip/hip_bf16.h>

#define B   128
#define NA  8
#define AD  16
#define DM  512
#define DI  1024
#define DS  32
#define DC  4
#define DR  32
#define NB  4
#define OD  128

typedef __hip_bfloat16 bf16;
typedef unsigned int uint32;
typedef unsigned short ushort16;

__device__ __forceinline__ float bf2f(bf16 h){ return __bfloat162float(h); }
__device__ __forceinline__ float sigmoidf_(float x){ return 1.0f/(1.0f+__expf(-x)); }
__device__ __forceinline__ float softplusf_(float x){ return fmaxf(x,0.0f)+log1pf(__expf(-fabsf(x))); }
__device__ __forceinline__ float lo2f(uint32 u){ return __uint_as_float(u<<16); }
__device__ __forceinline__ float hi2f(uint32 u){ return __uint_as_float(u & 0xffff0000u); }
__device__ __forceinline__ uint32 packbf2(float a, float b){
    bf16 ha = __float2bfloat16(a), hb = __float2bfloat16(b);
    ushort16 sa = *reinterpret_cast<ushort16*>(&ha);
    ushort16 sb = *reinterpret_cast<ushort16*>(&hb);
    return (uint32)sa | ((uint32)sb << 16);
}
__device__ __forceinline__ ushort16 f2us(float a){
    bf16 ha = __float2bfloat16(a);
    return *reinterpret_cast<ushort16*>(&ha);
}

// ---------------- init / conversion kernels (unchanged layouts) ----------------

__global__ __launch_bounds__(256) void k_negA(const float* __restrict__ Als,
    const float* __restrict__ Alc, float* __restrict__ negA)
{
    int idx = blockIdx.x*256 + threadIdx.x;   // < 2*NB*DI*DS = 262144
    int bs = idx >> 15;
    int r  = idx & 32767;
    int nb = bs >> 1, st = bs & 1;
    const float* src = (st ? Alc : Als) + (size_t)nb*DI*DS + r;
    negA[idx] = -__expf(*src);
}

__global__ __launch_bounds__(256) void k_ctx(const float* __restrict__ obs_rep,
    const float* __restrict__ obs, const float* __restrict__ Wobs,
    float* __restrict__ ctx)
{
    int ib = blockIdx.x;          // < B*8
    int b = ib >> 3, i = ib & 7;
    __shared__ float orow[OD];
    int tid = threadIdx.x;
    if (tid < OD) orow[tid] = obs[(size_t)(b*NA+i)*OD + tid];
    __syncthreads();
    for (int m = tid; m < DM; m += 256){
        float acc = obs_rep[(size_t)(b*NA+i)*DM + m];
        for (int o = 0; o < OD; o++)
            acc += orow[o]*Wobs[o*DM + m];
        ctx[(size_t)(i*B + b)*DM + m] = acc;
    }
}

// W1b[bs][k][c] bf16, [8][512][2048]
__global__ __launch_bounds__(256) void k_w1(const float* __restrict__ Ws,
    const float* __restrict__ Wc, ushort16* __restrict__ W1b)
{
    int idx = blockIdx.x*256 + threadIdx.x;   // < 8*1048576
    int bs = idx >> 20;
    int r  = idx & 1048575;
    int nb = bs >> 1, st = bs & 1;
    const float* src = (st ? Wc : Ws) + (size_t)nb*1048576 + r;
    W1b[idx] = f2us(*src);
}

// WoU[bs][k][p] = packed pair (cols 2p,2p+1) of out_proj (1024 x 512)
__global__ __launch_bounds__(256) void k_wo(const float* __restrict__ Ws,
    const float* __restrict__ Wc, uint32* __restrict__ WoU)
{
    int idx = blockIdx.x*256 + threadIdx.x;   // < 8*262144
    int bs = idx >> 18;
    int r  = idx & 262143;
    int k  = r >> 8, p = r & 255;
    int nb = bs >> 1, st = bs & 1;
    const float* src = (st ? Wc : Ws) + (size_t)nb*DI*DM + (size_t)k*DM + 2*p;
    WoU[idx] = packbf2(src[0], src[1]);
}

// Wxb[bs][j][k] bf16 — TRANSPOSED x_proj: [8][96][1024]
__global__ __launch_bounds__(256) void k_wx(const float* __restrict__ Ws,
    const float* __restrict__ Wc, ushort16* __restrict__ Wxb)
{
    int idx = blockIdx.x*256 + threadIdx.x;   // < 8*98304
    int bs = idx / 98304;
    int r  = idx % 98304;
    int j  = r >> 10, k = r & 1023;
    int nb = bs >> 1, st = bs & 1;
    const float* src = (st ? Wc : Ws) + (size_t)nb*DI*96 + (size_t)k*96 + j;
    Wxb[idx] = f2us(*src);
}

// Wdtb[bs][r][d] bf16 [8][32][1024]
__global__ __launch_bounds__(256) void k_wdt(const float* __restrict__ Ws,
    const float* __restrict__ Wc, ushort16* __restrict__ Wdtb)
{
    int idx = blockIdx.x*256 + threadIdx.x;   // < 8*32768
    int bs = idx >> 15;
    int r  = idx & 32767;
    int nb = bs >> 1, st = bs & 1;
    const float* src = (st ? Wc : Ws) + (size_t)nb*DR*DI + r;
    Wdtb[idx] = f2us(*src);
}

// x0 = bemb broadcast; zero 8 partial buffers pP[8][B][DM]
__global__ __launch_bounds__(256) void k_init(const float* __restrict__ bemb,
    float* __restrict__ xb0, float* __restrict__ pP)
{
    int idx = blockIdx.x*256 + threadIdx.x;   // < 8*B*DM = 524288
    if (idx < B*DM) xb0[idx] = bemb[idx & (DM-1)];
    pP[idx] = 0.f;
}

// ---------------- per-step kernels ----------------
// grid 256 = 32 rowgroups (R=4 rows) x 8 colgroups/chunks. blockIdx&7 -> fixed
// XCD (round-robin) so each XCD's L2 holds only its 256-col weight slice.

// step1: fold x + sum(pP[0..7]), LN(+ctx), gemm1 (256-col slice, K-chunks 4x128
// preserved), conv ring + silu -> xc (cg<4), xproj partial slice (cg<4), sz (cg>=4)
__global__ __launch_bounds__(512) void k_step1(
    const float* __restrict__ xin, const float* __restrict__ pP,
    float* __restrict__ xout, const float* __restrict__ lns,
    const float* __restrict__ ctxG, const bf16* __restrict__ W1b,
    const bf16* __restrict__ Wxb, const float* __restrict__ cw,
    const float* __restrict__ cb, uint32* __restrict__ convrU,
    float* __restrict__ xcG, float* __restrict__ szG,
    float* __restrict__ xpP, int i, int st, int bs)
{
    int rg = blockIdx.x >> 3, cg = blockIdx.x & 7;
    int t = threadIdx.x;
    __shared__ float ulnL[4][512];
    __shared__ float red1[4][4][256];   // [kchunk][row][col]
    __shared__ float xzL[4][256];       // later reused to hold xc (cg<4)
    __shared__ float wred[4][2][2];
    __shared__ float ms2[4][2];

    // ---- fold + LN: thread = (row r of 4, 4 consecutive cols) ----
    {
        int r = t >> 7, cq = t & 127;
        int row = rg*4 + r;
        float4 v4 = *(const float4*)&xin[(size_t)row*DM + cq*4];
        #pragma unroll
        for (int g = 0; g < 8; g++){
            float4 q4 = *(const float4*)&pP[((size_t)g*B + row)*DM + cq*4];
            v4.x += q4.x; v4.y += q4.y; v4.z += q4.z; v4.w += q4.w;
        }
        if (cg == 0) *(float4*)&xout[(size_t)row*DM + cq*4] = v4;
        float s = v4.x + v4.y + v4.z + v4.w;
        float q = v4.x*v4.x + v4.y*v4.y + v4.z*v4.z + v4.w*v4.w;
        #pragma unroll
        for (int off = 32; off > 0; off >>= 1){
            s += __shfl_down(s, off);
            q += __shfl_down(q, off);
        }
        int lane = t & 63, wid = t >> 6;   // wave covers one row-half
        if (lane == 0){ wred[wid>>1][wid&1][0] = s; wred[wid>>1][wid&1][1] = q; }
        __syncthreads();
        if (t < 4){
            float S = wred[t][0][0] + wred[t][1][0];
            float Q = wred[t][0][1] + wred[t][1][1];
            float m = S*(1.0f/DM);
            float var = Q*(1.0f/DM) - m*m;
            ms2[t][0] = m; ms2[t][1] = rsqrtf(var + 1e-5f);
        }
        __syncthreads();
        float m = ms2[r][0], rs = ms2[r][1];
        float4 l4 = *(const float4*)&lns[cq*4];
        float u0 = (v4.x - m)*rs*l4.x;
        float u1 = (v4.y - m)*rs*l4.y;
        float u2 = (v4.z - m)*rs*l4.z;
        float u3 = (v4.w - m)*rs*l4.w;
        if (st){
            float4 c4 = *(const float4*)&ctxG[((size_t)i*B + row)*DM + cq*4];
            u0 += c4.x; u1 += c4.y; u2 += c4.z; u3 += c4.w;
        }
        *(float4*)&ulnL[r][cq*4] = make_float4(u0,u1,u2,u3);
    }
    __syncthreads();

    // ---- gemm1: thread = (pack p of 32, row rr of 4, kchunk g of 4) ----
    // weight uint4 shared by the 4 rows -> broadcast/L1; traffic = 256KB/block
    {
        int p = t & 31, rr = (t>>5)&3, g = t >> 7;
        const uint4* wp4 = (const uint4*)(W1b + ((size_t)bs << 20));
        const float* ur = ulnL[rr];
        float a0=0.f,a1=0.f,a2=0.f,a3=0.f,a4=0.f,a5=0.f,a6=0.f,a7=0.f;
        int kbeg = g*128;
        size_t widx = (size_t)kbeg*256 + cg*32 + p;
        #pragma unroll 4
        for (int k = kbeg; k < kbeg + 128; k++, widx += 256){
            float a = ur[k];
            uint4 q4 = wp4[widx];
            a0 += a*lo2f(q4.x); a1 += a*hi2f(q4.x);
            a2 += a*lo2f(q4.y); a3 += a*hi2f(q4.y);
            a4 += a*lo2f(q4.z); a5 += a*hi2f(q4.z);
            a6 += a*lo2f(q4.w); a7 += a*hi2f(q4.w);
        }
        *(float4*)&red1[g][rr][p*8]     = make_float4(a0,a1,a2,a3);
        *(float4*)&red1[g][rr][p*8 + 4] = make_float4(a4,a5,a6,a7);
    }
    __syncthreads();
    #pragma unroll
    for (int z = 0; z < 2; z++){
        int idx = t + z*512;
        int r2 = idx >> 8, c = idx & 255;
        xzL[r2][c] = red1[0][r2][c] + red1[1][r2][c]
                   + red1[2][r2][c] + red1[3][r2][c];
    }
    __syncthreads();

    if (cg < 4){
        // ---- conv ring + silu -> xc for d in [cg*256, cg*256+256) ----
        {
            int r3 = t >> 7, pi = t & 127;
            int row3 = rg*4 + r3;
            int d0 = cg*256 + 2*pi;
            float xz0 = xzL[r3][2*pi], xz1 = xzL[r3][2*pi+1];
            uint32* ring = convrU + ((size_t)bs << 18);   // [4][128][512] uints
            size_t rb = (size_t)row3*512 + (d0>>1);
            ring[((size_t)(i&3))*65536 + rb] = packbf2(xz0, xz1);
            float s0 = cb[d0]   + cw[3*DI + d0]  *xz0;
            float s1 = cb[d0+1] + cw[3*DI + d0+1]*xz1;
            if (i >= 1){ uint32 uu = ring[((size_t)((i-1)&3))*65536 + rb];
                s0 += cw[2*DI + d0]*lo2f(uu); s1 += cw[2*DI + d0+1]*hi2f(uu); }
            if (i >= 2){ uint32 uu = ring[((size_t)((i-2)&3))*65536 + rb];
                s0 += cw[1*DI + d0]*lo2f(uu); s1 += cw[1*DI + d0+1]*hi2f(uu); }
            if (i >= 3){ uint32 uu = ring[((size_t)((i-3)&3))*65536 + rb];
                s0 += cw[0*DI + d0]*lo2f(uu); s1 += cw[0*DI + d0+1]*hi2f(uu); }
            float xc0 = s0*sigmoidf_(s0), xc1 = s1*sigmoidf_(s1);
            xcG[(size_t)row3*DI + d0]   = xc0;
            xcG[(size_t)row3*DI + d0+1] = xc1;
            xzL[r3][2*pi] = xc0; xzL[r3][2*pi+1] = xc1;  // own slots: no race
        }
        __syncthreads();
        // ---- xproj partial over this 256-k slice (same slice bounds as before) ----
        if (t < 384){
            int rx = t/96, j = t - rx*96;
            const uint4* wx4 = (const uint4*)(Wxb + (size_t)bs*98304
                                              + (size_t)j*1024 + cg*256);
            const float* xr = xzL[rx];
            float acc = 0.f;
            #pragma unroll 4
            for (int ii = 0; ii < 32; ii++){
                uint4 q4 = wx4[ii];
                int kk = 8*ii;
                acc += xr[kk+0]*lo2f(q4.x) + xr[kk+1]*hi2f(q4.x)
                     + xr[kk+2]*lo2f(q4.y) + xr[kk+3]*hi2f(q4.y)
                     + xr[kk+4]*lo2f(q4.z) + xr[kk+5]*hi2f(q4.z)
                     + xr[kk+6]*lo2f(q4.w) + xr[kk+7]*hi2f(q4.w);
            }
            xpP[((size_t)cg*B + rg*4 + rx)*96 + j] = acc;
        }
    } else {
        // ---- z path: sz = xz*silu'(xz) for d in [(cg-4)*256, +256) ----
        #pragma unroll
        for (int z = 0; z < 2; z++){
            int idx = t + z*512;
            int r2 = idx >> 8, c = idx & 255;
            int row2 = rg*4 + r2;
            int d = (cg-4)*256 + c;
            float xz = xzL[r2][c];
            szG[(size_t)row2*DI + d] = xz*sigmoidf_(xz);
        }
    }
}

// step2: rowS from 4 xproj slices, dt, h update + y (128-d chunk x 4 rows),
// gemm2 K-chunk -> pP[g]
__global__ __launch_bounds__(512) void k_step2(
    const float* __restrict__ xcG, const float* __restrict__ szG,
    const float* __restrict__ xpP, const bf16* __restrict__ Wdtb,
    const float* __restrict__ dtb, const float* __restrict__ Dp,
    const float* __restrict__ negA, const uint32* __restrict__ WoU,
    uint32* __restrict__ hG, float* __restrict__ pP,
    int first, int bs)
{
    int rg = blockIdx.x >> 3, g = blockIdx.x & 7;
    int t = threadIdx.x;
    __shared__ float rowS[4][96];
    __shared__ float yzL[4][128];

    if (t < 384){
        int rx = t/96, j = t - rx*96;
        int row0 = rg*4 + rx;
        size_t base = (size_t)row0*96 + j;
        rowS[rx][j] = xpP[base] + xpP[(size_t)B*96 + base]
                    + xpP[(size_t)2*B*96 + base] + xpP[(size_t)3*B*96 + base];
    }
    __syncthreads();

    {
        int r = t >> 7, dl = t & 127;
        int d = g*128 + dl;
        int row = rg*4 + r;
        float dp = dtb[d];
        const bf16* wdt = Wdtb + ((size_t)bs << 15);
        #pragma unroll 8
        for (int rr = 0; rr < DR; rr++)
            dp += rowS[r][rr]*bf2f(wdt[(size_t)rr*DI + d]);
        float delta = softplusf_(dp);
        float xcv = xcG[(size_t)row*DI + d];
        float dxc = delta*xcv;
        const float4* nap = (const float4*)(negA + ((size_t)bs << 15) + (size_t)d*DS);
        uint4* hp = (uint4*)(hG + (((size_t)bs*B + row)*DI + d)*16);
        float y = 0.f;
        #pragma unroll
        for (int qq = 0; qq < 4; qq++){
            uint4 hu = first ? make_uint4(0u,0u,0u,0u) : hp[qq];
            float4 na0 = nap[2*qq], na1 = nap[2*qq+1];
            int s0 = 8*qq;
            float h0 = lo2f(hu.x), h1 = hi2f(hu.x);
            float h2 = lo2f(hu.y), h3 = hi2f(hu.y);
            float h4 = lo2f(hu.z), h5 = hi2f(hu.z);
            float h6 = lo2f(hu.w), h7 = hi2f(hu.w);
            h0 = __expf(delta*na0.x)*h0 + dxc*rowS[r][DR+s0+0];
            h1 = __expf(delta*na0.y)*h1 + dxc*rowS[r][DR+s0+1];
            h2 = __expf(delta*na0.z)*h2 + dxc*rowS[r][DR+s0+2];
            h3 = __expf(delta*na0.w)*h3 + dxc*rowS[r][DR+s0+3];
            h4 = __expf(delta*na1.x)*h4 + dxc*rowS[r][DR+s0+4];
            h5 = __expf(delta*na1.y)*h5 + dxc*rowS[r][DR+s0+5];
            h6 = __expf(delta*na1.z)*h6 + dxc*rowS[r][DR+s0+6];
            h7 = __expf(delta*na1.w)*h7 + dxc*rowS[r][DR+s0+7];
            y += h0*rowS[r][DR+DS+s0+0] + h1*rowS[r][DR+DS+s0+1]
               + h2*rowS[r][DR+DS+s0+2] + h3*rowS[r][DR+DS+s0+3]
               + h4*rowS[r][DR+DS+s0+4] + h5*rowS[r][DR+DS+s0+5]
               + h6*rowS[r][DR+DS+s0+6] + h7*rowS[r][DR+DS+s0+7];
            hu.x = packbf2(h0,h1); hu.y = packbf2(h2,h3);
            hu.z = packbf2(h4,h5); hu.w = packbf2(h6,h7);
            hp[qq] = hu;
        }
        y += Dp[d]*xcv;
        yzL[r][dl] = y*szG[(size_t)row*DI + d];
    }
    __syncthreads();

    // gemm2: this block's 128-K chunk (global k = g*128+kk), all 512 cols, 4 rows
    {
        int c = t & 127, r2 = t >> 7;
        int row2 = rg*4 + r2;
        const uint2* wo2 = (const uint2*)(WoU + ((size_t)bs << 18));
        const float* yr = yzL[r2];
        float b0=0.f,b1=0.f,b2=0.f,b3=0.f;
        #pragma unroll 4
        for (int kk = 0; kk < 128; kk++){
            float av = yr[kk];
            uint2 u2 = wo2[(size_t)(g*128 + kk)*128 + c];
            b0 += av*lo2f(u2.x); b1 += av*hi2f(u2.x);
            b2 += av*lo2f(u2.y); b3 += av*hi2f(u2.y);
        }
        *(float4*)&pP[((size_t)g*B + row2)*DM + 4*c] = make_float4(b0,b1,b2,b3);
    }
}

// head: fold(8 partials), LN, W_head GEMV, outputs, next x, zero partials
__global__ __launch_bounds__(512) void k_head(
    const float* __restrict__ xin, float* __restrict__ xout,
    float* __restrict__ pP,
    const float* __restrict__ lno, const float* __restrict__ Whead,
    const float* __restrict__ logstd, const float* __restrict__ eps,
    const float* __restrict__ Wemb, const float* __restrict__ bemb,
    float* __restrict__ out, int agent)
{
    int b = blockIdx.x, t = threadIdx.x, lane = t & 63, wid = t >> 6;
    __shared__ float ulnL[512];
    __shared__ float redH[512];
    __shared__ float wps[8], wpq[8], ms2[2];
    __shared__ float actv[AD], lpterm[AD];

    float v = xin[(size_t)b*DM + t];
    #pragma unroll
    for (int g = 0; g < 8; g++) v += pP[((size_t)g*B + b)*DM + t];
    float s = v, q = v*v;
    for (int off = 32; off > 0; off >>= 1){
        s += __shfl_down(s, off);
        q += __shfl_down(q, off);
    }
    if (lane == 0){ wps[wid] = s; wpq[wid] = q; }
    __syncthreads();
    if (t == 0){
        float S = 0.f, Q = 0.f;
        #pragma unroll
        for (int w2 = 0; w2 < 8; w2++){ S += wps[w2]; Q += wpq[w2]; }
        float m = S*(1.0f/DM);
        float var = Q*(1.0f/DM) - m*m;
        ms2[0] = m; ms2[1] = rsqrtf(var + 1e-5f);
    }
    __syncthreads();
    ulnL[t] = (v - ms2[0])*ms2[1]*lno[t];
    __syncthreads();
    {
        int ks = t >> 4, j = t & 15;
        float acc = 0.f;
        int k0 = ks*16;
        #pragma unroll
        for (int k = k0; k < k0 + 16; k++)
            acc += ulnL[k]*Whead[k*AD + j];
        redH[t] = acc;
    }
    __syncthreads();
    if (t < AD){
        int j = t;
        float mean = 0.f;
        #pragma unroll
        for (int ks = 0; ks < 32; ks++) mean += redH[ks*16 + j];
        float stdj = softplusf_(logstd[j]);
        float e = eps[((size_t)b*NA + agent)*AD + j];
        float raw = mean + stdj*e;
        float act = tanhf(raw);
        out[((size_t)b*NA + agent)*AD + j] = act;                                    // acts
        out[(size_t)NA*B*AD + (size_t)B*NA + ((size_t)b*NA + agent)*AD + j] = raw;   // raws
        actv[j] = act;
        lpterm[j] = -0.5f*e*e - logf(stdj)
                    - 2.0f*(0.69314718f - raw - softplusf_(-2.0f*raw));
    }
    __syncthreads();
    if (t == 0){
        float lp = 0.f;
        #pragma unroll
        for (int j = 0; j < AD; j++) lp += lpterm[j];
        lp -= 0.5f*AD*1.8378770664f;
        out[(size_t)NA*B*AD + (size_t)b*NA + agent] = lp;                            // logs
    }
    float v2 = bemb[t];
    #pragma unroll
    for (int j = 0; j < AD; j++)
        v2 += actv[j]*Wemb[j*DM + t];
    xout[(size_t)b*DM + t] = v2;
    #pragma unroll
    for (int g = 0; g < 8; g++) pP[((size_t)g*B + b)*DM + t] = 0.f;
}

// ---------------- launch ----------------

extern "C" void kernel_launch(void* const* d_in, const int* in_sizes, int n_in,
                              void* d_out, int out_size, void* d_ws, size_t ws_size,
                              hipStream_t stream)
{
    const float* in[29];
    for (int k = 0; k < 29; k++) in[k] = (const float*)d_in[k];

    // workspace layout (bytes), total ~109.8 MB (ws is 256 MB per poison-fill evidence)
    char* wsb = (char*)d_ws;
    bf16*   W1b  = (bf16*)  (wsb + 0);           // 16,777,216
    uint32* WoU  = (uint32*)(wsb + 16777216);    //  8,388,608
    bf16*   Wxb  = (bf16*)  (wsb + 25165824);    //  1,572,864
    bf16*   Wdtb = (bf16*)  (wsb + 26738688);    //    524,288
    float*  negA = (float*) (wsb + 27262976);    //  1,048,576
    float*  ctx  = (float*) (wsb + 28311552);    //  2,097,152
    float*  xb0  = (float*) (wsb + 30408704);    //    262,144
    float*  xb1  = (float*) (wsb + 30670848);    //    262,144
    float*  xcG  = (float*) (wsb + 30932992);    //    524,288
    float*  szG  = (float*) (wsb + 31457280);    //    524,288
    float*  xpP  = (float*) (wsb + 31981568);    //    262,144 (uses 196,608)
    float*  pP   = (float*) (wsb + 32243712);    //  2,097,152  [8][B][DM]
    uint32* convrU = (uint32*)(wsb + 34340864);  //  8,388,608
    uint32* hG   = (uint32*)(wsb + 42729472);    // 67,108,864  (end 109,838,336)

    float* out = (float*)d_out;
    float* xb[2] = {xb0, xb1};

    k_negA<<<dim3(1024),  256, 0, stream>>>(in[17], in[26], negA);
    k_ctx <<<dim3(B*NA),  256, 0, stream>>>(in[0], in[1], in[5], ctx);
    k_w1  <<<dim3(32768), 256, 0, stream>>>(in[11], in[20], (ushort16*)W1b);
    k_wo  <<<dim3(8192),  256, 0, stream>>>(in[19], in[28], WoU);
    k_wx  <<<dim3(3072),  256, 0, stream>>>(in[14], in[23], (ushort16*)Wxb);
    k_wdt <<<dim3(1024),  256, 0, stream>>>(in[15], in[24], (ushort16*)Wdtb);
    k_init<<<dim3(2048),  256, 0, stream>>>(in[4], xb0, pP);

    int cur = 0;
    for (int i = 0; i < NA; i++){
        for (int nb = 0; nb < NB; nb++){
            for (int st = 0; st < 2; st++){
                int bs = nb*2 + st;
                int base = st ? 20 : 11;
                const float* cw   = in[base+1] + (size_t)nb*DC*DI;
                const float* cb   = in[base+2] + (size_t)nb*DI;
                const float* dtbp = in[base+5] + (size_t)nb*DI;
                const float* Dpp  = in[base+7] + (size_t)nb*DI;
                const float* lns  = (st ? in[7] : in[6]) + (size_t)nb*DM;

                k_step1<<<dim3(256), 512, 0, stream>>>(xb[cur], pP, xb[cur^1],
                        lns, ctx, W1b, Wxb, cw, cb, convrU, xcG, szG, xpP, i, st, bs);
                cur ^= 1;
                k_step2<<<dim3(256), 512, 0, stream>>>(xcG, szG, xpP, Wdtb,
                        dtbp, Dpp, negA, WoU, hG, pP, (i==0) ? 1 : 0, bs);
            }
        }
        k_head<<<dim3(B), 512, 0, stream>>>(xb[cur], xb[cur^1], pP,
                in[8], in[9], in[10], in[2], in[3], in[4], out, i);
        cur ^= 1;
    }
}